// Round 5
// baseline (289.733 us; speedup 1.0000x reference)
//
#include <hip/hip_runtime.h>
#include <math.h>

#define ROWS   8192
#define LQ     4096
#define NHEAD  8
#define NLVL   4
#define NPTS   4
#define HDIM   32

typedef __attribute__((ext_vector_type(8))) short v8s;
typedef __attribute__((ext_vector_type(4))) float v4f;

__device__ __forceinline__ unsigned short f2bf(float x) {
    unsigned int u = __float_as_uint(x);
    u += 0x7fffu + ((u >> 16) & 1u);
    return (unsigned short)(u >> 16);
}
__device__ __forceinline__ float bf2f(unsigned short x) {
    return __uint_as_float(((unsigned int)x) << 16);
}

// ---------------------------------------------------------------------------
// fp32 -> bf16 elementwise (vectorized x4)
// ---------------------------------------------------------------------------
__global__ __launch_bounds__(256) void f2bf_k(const float* __restrict__ in,
                                              unsigned short* __restrict__ out, int n4)
{
    int i = blockIdx.x * 256 + threadIdx.x;
    if (i >= n4) return;
    float4 v = ((const float4*)in)[i];
    ushort4 o;
    o.x = f2bf(v.x); o.y = f2bf(v.y); o.z = f2bf(v.z); o.w = f2bf(v.w);
    ((ushort4*)out)[i] = o;
}

// ---------------------------------------------------------------------------
// Transpose + convert: out_bf[(n_off + n) * ldout + k] = bf16(in[k*N + n])
// ---------------------------------------------------------------------------
__global__ __launch_bounds__(256) void transT_k(const float* __restrict__ in,
                                                unsigned short* __restrict__ out,
                                                int K, int N, int ldout, int n_off)
{
    __shared__ float t[32][33];
    int tid = threadIdx.x;
    int tx = tid & 31, ty = tid >> 5;           // 32 x 8
    int k0 = blockIdx.y << 5, n0 = blockIdx.x << 5;
    #pragma unroll
    for (int i = 0; i < 4; i++)
        t[ty + i * 8][tx] = in[(size_t)(k0 + ty + i * 8) * N + n0 + tx];
    __syncthreads();
    #pragma unroll
    for (int i = 0; i < 4; i++)
        out[(size_t)(n_off + n0 + ty + i * 8) * ldout + k0 + tx] = f2bf(t[tx][ty + i * 8]);
}

// ---------------------------------------------------------------------------
// Concatenate 3 bias vectors (256 + 256 + 128)
// ---------------------------------------------------------------------------
__global__ __launch_bounds__(256) void biascat_k(const float* __restrict__ a,
                                                 const float* __restrict__ b,
                                                 const float* __restrict__ c,
                                                 float* __restrict__ out)
{
    int i = blockIdx.x * 256 + threadIdx.x;
    if (i < 256) out[i] = a[i];
    else if (i < 512) out[i] = b[i - 256];
    else if (i < 640) out[i] = c[i - 512];
}

// ---------------------------------------------------------------------------
// bf16 MFMA GEMM: C[M][N] = A[M][K] @ Bt[N][K]^T + bias (+res)(relu)
// BM=128, BN=64, BK=64; 256 threads = 4 waves (2x2), each wave 64x32.
// Register-prefetch double buffering: load tile k+1 during compute of k.
// LDS layout [q][row][8] (q = K/8 chunk); staging mapping q-inner so both
// global loads (128B per 8 lanes) and LDS b128 ops sit at the bank floor.
// PROJ mode (N=640): cols [0,256) scatter bf16 into compact value layout
// [ (b*4+l)*8+h ][pix][d] ; cols [256,640) -> po[row][col-256] fp32.
// ---------------------------------------------------------------------------
template<bool PROJ, bool OUTBF, bool RELU, bool RES>
__global__ __launch_bounds__(256) void mfma_gemm_k(
    const unsigned short* __restrict__ A,   // bf16 [M][K]
    const unsigned short* __restrict__ Bt,  // bf16 [N][K]
    const float* __restrict__ bias,
    const float* __restrict__ res,
    void* __restrict__ Cout,
    unsigned short* __restrict__ vbf,       // PROJ only
    int M, int N, int K)
{
    __shared__ __align__(16) unsigned short As[8][128][8];  // 16 KB
    __shared__ __align__(16) unsigned short Bs[8][64][8];   //  8 KB
    const int tid = threadIdx.x;
    const int row0 = blockIdx.y << 7, col0 = blockIdx.x << 6;
    const int wid = tid >> 6, lane = tid & 63;
    const int wm = wid & 1, wn = wid >> 1;
    const int lr = lane & 15, kq = lane >> 4;
    // staging: A has 1024 16B-chunks (4/thread), B has 512 (2/thread)
    const int ra = tid >> 3, qa = tid & 7;    // +32 rows per i

    v4f acc[4][2];
    #pragma unroll
    for (int i = 0; i < 4; i++)
        #pragma unroll
        for (int j = 0; j < 2; j++) acc[i][j] = (v4f){0.f, 0.f, 0.f, 0.f};

    float4 a_reg[4], b_reg[2];

#define LOAD_TILE(k0)                                                          \
    {                                                                          \
        _Pragma("unroll")                                                      \
        for (int i = 0; i < 4; i++)                                            \
            a_reg[i] = *(const float4*)(A + (size_t)(row0 + ra + i * 32) * K + \
                                        (k0) + qa * 8);                        \
        _Pragma("unroll")                                                      \
        for (int i = 0; i < 2; i++)                                            \
            b_reg[i] = *(const float4*)(Bt + (size_t)(col0 + ra + i * 32) * K +\
                                        (k0) + qa * 8);                        \
    }

    LOAD_TILE(0)
    for (int k0 = 0; k0 < K; k0 += 64) {
        __syncthreads();
        #pragma unroll
        for (int i = 0; i < 4; i++)
            *(float4*)(&As[qa][ra + i * 32][0]) = a_reg[i];
        #pragma unroll
        for (int i = 0; i < 2; i++)
            *(float4*)(&Bs[qa][ra + i * 32][0]) = b_reg[i];
        __syncthreads();
        if (k0 + 64 < K) LOAD_TILE(k0 + 64)
        #pragma unroll
        for (int step = 0; step < 2; step++) {
            int q = step * 4 + kq;
            v8s bf[2];
            #pragma unroll
            for (int nt = 0; nt < 2; nt++)
                bf[nt] = *(const v8s*)(&Bs[q][wn * 32 + nt * 16 + lr][0]);
            #pragma unroll
            for (int mt = 0; mt < 4; mt++) {
                v8s af = *(const v8s*)(&As[q][wm * 64 + mt * 16 + lr][0]);
                #pragma unroll
                for (int nt = 0; nt < 2; nt++)
                    acc[mt][nt] = __builtin_amdgcn_mfma_f32_16x16x32_bf16(
                        af, bf[nt], acc[mt][nt], 0, 0, 0);
            }
        }
    }
#undef LOAD_TILE

    const int rq = lane >> 4;
    #pragma unroll
    for (int mt = 0; mt < 4; mt++) {
        #pragma unroll
        for (int nt = 0; nt < 2; nt++) {
            int col = col0 + wn * 32 + nt * 16 + lr;
            float bv = bias[col];
            #pragma unroll
            for (int i = 0; i < 4; i++) {
                int row = row0 + wm * 64 + mt * 16 + rq * 4 + i;
                float v = acc[mt][nt][i] + bv;
                if (RELU) v = fmaxf(v, 0.f);
                if (RES)  v += res[(size_t)row * N + col];
                if (PROJ) {
                    if (col0 < 256) {
                        int b = row >> 12, rb = row & 4095;
                        int l = rb >> 10, pix = rb & 1023;
                        int h = col >> 5, d = col & 31;
                        size_t idx = ((size_t)(((b << 2) + l) * 8 + h) << 15) + (pix << 5) + d;
                        vbf[idx] = f2bf(v);
                    } else {
                        ((float*)Cout)[(size_t)row * 384 + col - 256] = v;
                    }
                } else if (OUTBF) {
                    ((unsigned short*)Cout)[(size_t)row * N + col] = f2bf(v);
                } else {
                    ((float*)Cout)[(size_t)row * N + col] = v;
                }
            }
        }
    }
}

// ---------------------------------------------------------------------------
// Fused: sampling-loc compute (+write), softmax-16, bilinear gather.
// 8 lanes per (r,h) group; lane covers 4 dims (8 lanes x ushort4 = one 64B
// line per tap). Taps of each level staged into register arrays (16-deep
// load pipeline) before accumulation.
// ---------------------------------------------------------------------------
__global__ __launch_bounds__(256) void fused_gather_k(
    const float* __restrict__ po,              // [ROWS][384] offsets|logits
    const unsigned short* __restrict__ vbf,    // [64][1024][32] bf16
    const float* __restrict__ refp,            // [ROWS][8]
    float* __restrict__ out_loc,               // [ROWS][256]
    unsigned short* __restrict__ attn_bf)      // [ROWS][256] bf16
{
    int tid = threadIdx.x;
    int grp = tid >> 3, d4 = tid & 7;
    int gid = blockIdx.x * 32 + grp;           // r*8 + h
    int h = gid & 7, r = gid >> 3;
    int b = r >> 12;
    const float* prow = po + (size_t)r * 384;

    float rp[8];
    *(float4*)(rp)     = *(const float4*)(refp + (size_t)r * 8);
    *(float4*)(rp + 4) = *(const float4*)(refp + (size_t)r * 8 + 4);

    float loc[32];
    #pragma unroll
    for (int i = 0; i < 8; i++)
        *(float4*)(loc + i * 4) = *(const float4*)(prow + h * 32 + i * 4);
    #pragma unroll
    for (int i = 0; i < 32; i++) {
        int l = i >> 3, c = i & 1;
        loc[i] = rp[l * 2 + c] + loc[i] * (1.f / 32.f);
    }
    *(float4*)(out_loc + (size_t)r * 256 + h * 32 + d4 * 4) = *(const float4*)(loc + d4 * 4);

    float w[16];
    #pragma unroll
    for (int i = 0; i < 4; i++)
        *(float4*)(w + i * 4) = *(const float4*)(prow + 256 + h * 16 + i * 4);
    float m = -1e30f;
    #pragma unroll
    for (int i = 0; i < 16; i++) m = fmaxf(m, w[i]);
    float s = 0.f;
    #pragma unroll
    for (int i = 0; i < 16; i++) { w[i] = __expf(w[i] - m); s += w[i]; }
    float inv = 1.f / s;
    #pragma unroll
    for (int i = 0; i < 16; i++) w[i] *= inv;

    float4 acc = {0.f, 0.f, 0.f, 0.f};
    #pragma unroll
    for (int l = 0; l < 4; l++) {
        const unsigned short* vbase =
            vbf + (((size_t)(((b << 2) + l) * 8 + h)) << 15) + d4 * 4;
        ushort4 u[16];
        float cw[16];
        #pragma unroll
        for (int p = 0; p < 4; p++) {
            float lx = loc[l * 8 + p * 2], ly = loc[l * 8 + p * 2 + 1];
            float wgt = w[l * 4 + p];
            float xf = lx * 32.f - 0.5f, yf = ly * 32.f - 0.5f;
            float x0f = floorf(xf), y0f = floorf(yf);
            float fx = xf - x0f, fy = yf - y0f;
            int x0 = (int)x0f, y0 = (int)y0f;
            #pragma unroll
            for (int dy = 0; dy < 2; dy++) {
                #pragma unroll
                for (int dx = 0; dx < 2; dx++) {
                    int idx = p * 4 + dy * 2 + dx;
                    int xi = x0 + dx, yi = y0 + dy;
                    float wt = (dx ? fx : 1.f - fx) * (dy ? fy : 1.f - fy);
                    bool valid = (xi >= 0) & (xi < 32) & (yi >= 0) & (yi < 32);
                    int xc = min(max(xi, 0), 31), yc = min(max(yi, 0), 31);
                    cw[idx] = valid ? (wgt * wt) : 0.f;
                    u[idx] = *(const ushort4*)(vbase + (size_t)((yc << 5) + xc) * 32);
                }
            }
        }
        #pragma unroll
        for (int idx = 0; idx < 16; idx++) {
            float c = cw[idx];
            acc.x += c * bf2f(u[idx].x); acc.y += c * bf2f(u[idx].y);
            acc.z += c * bf2f(u[idx].z); acc.w += c * bf2f(u[idx].w);
        }
    }
    ushort4 o;
    o.x = f2bf(acc.x); o.y = f2bf(acc.y); o.z = f2bf(acc.z); o.w = f2bf(acc.w);
    *(ushort4*)(attn_bf + (size_t)r * 256 + h * 32 + d4 * 4) = o;
}

// ---------------------------------------------------------------------------
// In-place LayerNorm over 256 cols; optional bf16 copy-out.
// ---------------------------------------------------------------------------
template<bool WRITE_BF>
__global__ __launch_bounds__(256) void layernorm_k(
    float* __restrict__ x, const float* __restrict__ g, const float* __restrict__ b,
    unsigned short* __restrict__ xbf)
{
    int lane = threadIdx.x & 63;
    int wv = threadIdx.x >> 6;
    int row = blockIdx.x * 4 + wv;
    int c = lane << 2;
    float4 v = *(const float4*)(x + (size_t)row * 256 + c);
    float s = v.x + v.y + v.z + v.w;
    #pragma unroll
    for (int o = 1; o < 64; o <<= 1) s += __shfl_xor(s, o);
    float mu = s * (1.f / 256.f);
    float d0 = v.x - mu, d1 = v.y - mu, d2 = v.z - mu, d3 = v.w - mu;
    float vs = d0 * d0 + d1 * d1 + d2 * d2 + d3 * d3;
    #pragma unroll
    for (int o = 1; o < 64; o <<= 1) vs += __shfl_xor(vs, o);
    float rstd = rsqrtf(vs * (1.f / 256.f) + 1e-5f);
    float4 gg = *(const float4*)(g + c);
    float4 bb = *(const float4*)(b + c);
    float4 o4;
    o4.x = d0 * rstd * gg.x + bb.x;
    o4.y = d1 * rstd * gg.y + bb.y;
    o4.z = d2 * rstd * gg.z + bb.z;
    o4.w = d3 * rstd * gg.w + bb.w;
    *(float4*)(x + (size_t)row * 256 + c) = o4;
    if (WRITE_BF) {
        ushort4 ob;
        ob.x = f2bf(o4.x); ob.y = f2bf(o4.y); ob.z = f2bf(o4.z); ob.w = f2bf(o4.w);
        *(ushort4*)(xbf + (size_t)row * 256 + c) = ob;
    }
}

// ---------------------------------------------------------------------------
extern "C" void kernel_launch(void* const* d_in, const int* in_sizes, int n_in,
                              void* d_out, int out_size, void* d_ws, size_t ws_size,
                              hipStream_t stream)
{
    const float* src   = (const float*)d_in[0];
    const float* refp  = (const float*)d_in[2];
    const float* vw    = (const float*)d_in[3];
    const float* vb    = (const float*)d_in[4];
    const float* ofw   = (const float*)d_in[5];
    const float* ofb   = (const float*)d_in[6];
    const float* aww   = (const float*)d_in[7];
    const float* awb   = (const float*)d_in[8];
    const float* pw    = (const float*)d_in[9];
    const float* pb    = (const float*)d_in[10];
    const float* g1    = (const float*)d_in[11];
    const float* b1    = (const float*)d_in[12];
    const float* w1    = (const float*)d_in[13];
    const float* bi1   = (const float*)d_in[14];
    const float* w2    = (const float*)d_in[15];
    const float* bi2   = (const float*)d_in[16];
    const float* g2    = (const float*)d_in[17];
    const float* b2    = (const float*)d_in[18];

    float* ws = (float*)d_ws;
    float*          po        = ws;                               // 3,145,728 f
    float*          x1        = ws + 3145728;                     // 2,097,152 f
    unsigned short* value_bf  = (unsigned short*)(ws + 5242880);  // 2,097,152 us
    unsigned short* src_bf    = (unsigned short*)(ws + 6291456);  // 2,097,152 us
    unsigned short* x1_bf     = (unsigned short*)(ws + 7340032);
    unsigned short* attn_bf   = (unsigned short*)(ws + 8388608);
    unsigned short* hidden_bf = (unsigned short*)(ws + 9437184);  // 8,388,608 us
    unsigned short* Btcat     = (unsigned short*)(ws + 13631488); // 163,840 us
    unsigned short* pwT       = (unsigned short*)(ws + 13713408);
    unsigned short* w1T       = (unsigned short*)(ws + 13746176);
    unsigned short* w2T       = (unsigned short*)(ws + 13877248);
    float*          biascat   = ws + 14008320;                    // 640 f

    float* out_x   = (float*)d_out;
    float* out_loc = out_x + 2097152;

    dim3 blk(256);

    // --- weight prep (bf16, transposed) + src conversion ---
    f2bf_k<<<2048, blk, 0, stream>>>(src, src_bf, 524288);
    transT_k<<<dim3(8, 8),  blk, 0, stream>>>(vw,  Btcat, 256, 256,  256, 0);
    transT_k<<<dim3(8, 8),  blk, 0, stream>>>(ofw, Btcat, 256, 256,  256, 256);
    transT_k<<<dim3(4, 8),  blk, 0, stream>>>(aww, Btcat, 256, 128,  256, 512);
    transT_k<<<dim3(8, 8),  blk, 0, stream>>>(pw,  pwT,   256, 256,  256, 0);
    transT_k<<<dim3(32, 8), blk, 0, stream>>>(w1,  w1T,   256, 1024, 256, 0);
    transT_k<<<dim3(8, 32), blk, 0, stream>>>(w2,  w2T,  1024, 256, 1024, 0);
    biascat_k<<<3, blk, 0, stream>>>(vb, ofb, awb, biascat);

    // --- fused projections -> value_bf (compact) + po[8192][384]
    mfma_gemm_k<true, false, false, false><<<dim3(10, 64), blk, 0, stream>>>(
        src_bf, Btcat, biascat, nullptr, po, value_bf, ROWS, 640, 256);

    // --- loc + softmax + deformable gather -> out_loc, attn_bf
    fused_gather_k<<<2048, blk, 0, stream>>>(po, value_bf, refp, out_loc, attn_bf);

    // --- output projection + residual(src) -> x1, LN1 (+bf16 copy)
    mfma_gemm_k<false, false, false, true><<<dim3(4, 64), blk, 0, stream>>>(
        attn_bf, pwT, pb, src, x1, nullptr, ROWS, 256, 256);
    layernorm_k<true><<<2048, blk, 0, stream>>>(x1, g1, b1, x1_bf);

    // --- FFN ---
    mfma_gemm_k<false, true, true, false><<<dim3(16, 64), blk, 0, stream>>>(
        x1_bf, w1T, bi1, nullptr, hidden_bf, nullptr, ROWS, 1024, 256);
    mfma_gemm_k<false, false, false, true><<<dim3(4, 64), blk, 0, stream>>>(
        hidden_bf, w2T, bi2, x1, out_x, nullptr, ROWS, 256, 1024);
    layernorm_k<false><<<2048, blk, 0, stream>>>(out_x, g2, b2, nullptr);
}

// Round 6
// 207.299 us; speedup vs baseline: 1.3977x; 1.3977x over previous
//
#include <hip/hip_runtime.h>
#include <math.h>

#define ROWS   8192
#define LQ     4096
#define NHEAD  8
#define NLVL   4
#define NPTS   4
#define HDIM   32

typedef __attribute__((ext_vector_type(8))) short v8s;
typedef __attribute__((ext_vector_type(4))) float v4f;

__device__ __forceinline__ unsigned short f2bf(float x) {
    unsigned int u = __float_as_uint(x);
    u += 0x7fffu + ((u >> 16) & 1u);
    return (unsigned short)(u >> 16);
}
__device__ __forceinline__ float bf2f(unsigned short x) {
    return __uint_as_float(((unsigned int)x) << 16);
}

// ---------------------------------------------------------------------------
// fp32 -> bf16 elementwise (vectorized x4)
// ---------------------------------------------------------------------------
__global__ __launch_bounds__(256) void f2bf_k(const float* __restrict__ in,
                                              unsigned short* __restrict__ out, int n4)
{
    int i = blockIdx.x * 256 + threadIdx.x;
    if (i >= n4) return;
    float4 v = ((const float4*)in)[i];
    ushort4 o;
    o.x = f2bf(v.x); o.y = f2bf(v.y); o.z = f2bf(v.z); o.w = f2bf(v.w);
    ((ushort4*)out)[i] = o;
}

// ---------------------------------------------------------------------------
// Transpose + convert: out_bf[(n_off + n) * ldout + k] = bf16(in[k*N + n])
// ---------------------------------------------------------------------------
__global__ __launch_bounds__(256) void transT_k(const float* __restrict__ in,
                                                unsigned short* __restrict__ out,
                                                int K, int N, int ldout, int n_off)
{
    __shared__ float t[32][33];
    int tid = threadIdx.x;
    int tx = tid & 31, ty = tid >> 5;           // 32 x 8
    int k0 = blockIdx.y << 5, n0 = blockIdx.x << 5;
    #pragma unroll
    for (int i = 0; i < 4; i++)
        t[ty + i * 8][tx] = in[(size_t)(k0 + ty + i * 8) * N + n0 + tx];
    __syncthreads();
    #pragma unroll
    for (int i = 0; i < 4; i++)
        out[(size_t)(n_off + n0 + ty + i * 8) * ldout + k0 + tx] = f2bf(t[tx][ty + i * 8]);
}

// ---------------------------------------------------------------------------
// Concatenate 3 bias vectors (256 + 256 + 128)
// ---------------------------------------------------------------------------
__global__ __launch_bounds__(256) void biascat_k(const float* __restrict__ a,
                                                 const float* __restrict__ b,
                                                 const float* __restrict__ c,
                                                 float* __restrict__ out)
{
    int i = blockIdx.x * 256 + threadIdx.x;
    if (i < 256) out[i] = a[i];
    else if (i < 512) out[i] = b[i - 256];
    else if (i < 640) out[i] = c[i - 512];
}

// ---------------------------------------------------------------------------
// bf16 MFMA GEMM (R3-proven): BM=128, BN=64, BK=32; 256 threads = 4 waves
// (2x2), each wave 64x32 via 4x2 tiles of 16x16x32 MFMA. LDS [kq][row][8].
// PROJ mode (N=640): cols [0,256) scatter bf16 into compact value layout
// [ (b*4+l)*8+h ][pix][d] ; cols [256,640) -> po[row][col-256] fp32.
// ---------------------------------------------------------------------------
template<bool PROJ, bool OUTBF, bool RELU, bool RES>
__global__ __launch_bounds__(256) void mfma_gemm_k(
    const unsigned short* __restrict__ A,   // bf16 [M][K]
    const unsigned short* __restrict__ Bt,  // bf16 [N][K]
    const float* __restrict__ bias,
    const float* __restrict__ res,
    void* __restrict__ Cout,
    unsigned short* __restrict__ vbf,       // PROJ only
    int M, int N, int K)
{
    __shared__ __align__(16) unsigned short As[4][128][8];
    __shared__ __align__(16) unsigned short Bs[4][64][8];
    const int tid = threadIdx.x;
    const int row0 = blockIdx.y << 7, col0 = blockIdx.x << 6;
    const int wid = tid >> 6, lane = tid & 63;
    const int wm = wid & 1, wn = wid >> 1;
    const int lr = lane & 15, kq = lane >> 4;
    const int ar = tid >> 2, akq = tid & 3;
    const int bn = tid >> 2, bkq = tid & 3;

    v4f acc[4][2];
    #pragma unroll
    for (int i = 0; i < 4; i++)
        #pragma unroll
        for (int j = 0; j < 2; j++) acc[i][j] = (v4f){0.f, 0.f, 0.f, 0.f};

    for (int k0 = 0; k0 < K; k0 += 32) {
        float4 a0 = *(const float4*)(A + (size_t)(row0 + ar) * K + k0 + akq * 8);
        float4 a1 = *(const float4*)(A + (size_t)(row0 + ar + 64) * K + k0 + akq * 8);
        float4 b0 = *(const float4*)(Bt + (size_t)(col0 + bn) * K + k0 + bkq * 8);
        __syncthreads();
        *(float4*)(&As[akq][ar][0]) = a0;
        *(float4*)(&As[akq][ar + 64][0]) = a1;
        *(float4*)(&Bs[bkq][bn][0]) = b0;
        __syncthreads();
        v8s bf[2];
        #pragma unroll
        for (int nt = 0; nt < 2; nt++)
            bf[nt] = *(const v8s*)(&Bs[kq][wn * 32 + nt * 16 + lr][0]);
        #pragma unroll
        for (int mt = 0; mt < 4; mt++) {
            v8s af = *(const v8s*)(&As[kq][wm * 64 + mt * 16 + lr][0]);
            #pragma unroll
            for (int nt = 0; nt < 2; nt++)
                acc[mt][nt] = __builtin_amdgcn_mfma_f32_16x16x32_bf16(af, bf[nt], acc[mt][nt], 0, 0, 0);
        }
    }

    const int rq = lane >> 4;
    #pragma unroll
    for (int mt = 0; mt < 4; mt++) {
        #pragma unroll
        for (int nt = 0; nt < 2; nt++) {
            int col = col0 + wn * 32 + nt * 16 + lr;
            float bv = bias[col];
            #pragma unroll
            for (int i = 0; i < 4; i++) {
                int row = row0 + wm * 64 + mt * 16 + rq * 4 + i;
                float v = acc[mt][nt][i] + bv;
                if (RELU) v = fmaxf(v, 0.f);
                if (RES)  v += res[(size_t)row * N + col];
                if (PROJ) {
                    if (col0 < 256) {
                        int b = row >> 12, rb = row & 4095;
                        int l = rb >> 10, pix = rb & 1023;
                        int h = col >> 5, d = col & 31;
                        size_t idx = ((size_t)(((b << 2) + l) * 8 + h) << 15) + (pix << 5) + d;
                        vbf[idx] = f2bf(v);
                    } else {
                        ((float*)Cout)[(size_t)row * 384 + col - 256] = v;
                    }
                } else if (OUTBF) {
                    ((unsigned short*)Cout)[(size_t)row * N + col] = f2bf(v);
                } else {
                    ((float*)Cout)[(size_t)row * N + col] = v;
                }
            }
        }
    }
}

// ---------------------------------------------------------------------------
// Fused gather, level-split: thread (unit u, level l, d4) owns one level of
// one (r,h): 16 taps staged in registers. Softmax-16 and the final level
// reduction use __shfl_xor(8/16) within the 32-lane unit — no LDS/barriers.
// 4x the waves of the per-(r,h) version -> 4x memory-level parallelism.
// ---------------------------------------------------------------------------
__global__ __launch_bounds__(256) void fused_gather_k(
    const float* __restrict__ po,              // [ROWS][384] offsets|logits
    const unsigned short* __restrict__ vbf,    // [64][1024][32] bf16
    const float* __restrict__ refp,            // [ROWS][8]
    float* __restrict__ out_loc,               // [ROWS][256]
    unsigned short* __restrict__ attn_bf)      // [ROWS][256] bf16
{
    int tid = threadIdx.x;
    int u = tid >> 5, l = (tid >> 3) & 3, d4 = tid & 7;
    int gid = blockIdx.x * 8 + u;              // r*8 + h
    int h = gid & 7, r = gid >> 3;
    int b = r >> 12;
    const float* prow = po + (size_t)r * 384;

    float2 rp = *(const float2*)(refp + (size_t)r * 8 + l * 2);

    float off[8];
    *(float4*)(off)     = *(const float4*)(prow + h * 32 + l * 8);
    *(float4*)(off + 4) = *(const float4*)(prow + h * 32 + l * 8 + 4);
    float locv[8];
    #pragma unroll
    for (int k = 0; k < 8; k++)
        locv[k] = ((k & 1) ? rp.y : rp.x) + off[k] * (1.f / 32.f);
    out_loc[(size_t)r * 256 + h * 32 + l * 8 + d4] = locv[d4];

    float w4[4];
    *(float4*)(w4) = *(const float4*)(prow + 256 + h * 16 + l * 4);
    float m = fmaxf(fmaxf(w4[0], w4[1]), fmaxf(w4[2], w4[3]));
    m = fmaxf(m, __shfl_xor(m, 8));
    m = fmaxf(m, __shfl_xor(m, 16));
    float s = 0.f;
    #pragma unroll
    for (int p = 0; p < 4; p++) { w4[p] = __expf(w4[p] - m); s += w4[p]; }
    s += __shfl_xor(s, 8);
    s += __shfl_xor(s, 16);
    float inv = 1.f / s;

    const unsigned short* vbase =
        vbf + (((size_t)(((b << 2) + l) * 8 + h)) << 15) + d4 * 4;
    ushort4 uv[16];
    float cw[16];
    #pragma unroll
    for (int p = 0; p < 4; p++) {
        float xf = locv[p * 2] * 32.f - 0.5f, yf = locv[p * 2 + 1] * 32.f - 0.5f;
        float x0f = floorf(xf), y0f = floorf(yf);
        float fx = xf - x0f, fy = yf - y0f;
        int x0 = (int)x0f, y0 = (int)y0f;
        float wgt = w4[p] * inv;
        #pragma unroll
        for (int dy = 0; dy < 2; dy++) {
            #pragma unroll
            for (int dx = 0; dx < 2; dx++) {
                int idx = p * 4 + dy * 2 + dx;
                int xi = x0 + dx, yi = y0 + dy;
                float wt = (dx ? fx : 1.f - fx) * (dy ? fy : 1.f - fy);
                bool valid = (xi >= 0) & (xi < 32) & (yi >= 0) & (yi < 32);
                int xc = min(max(xi, 0), 31), yc = min(max(yi, 0), 31);
                cw[idx] = valid ? (wgt * wt) : 0.f;
                uv[idx] = *(const ushort4*)(vbase + (size_t)((yc << 5) + xc) * 32);
            }
        }
    }
    float4 acc = {0.f, 0.f, 0.f, 0.f};
    #pragma unroll
    for (int idx = 0; idx < 16; idx++) {
        float c = cw[idx];
        acc.x += c * bf2f(uv[idx].x); acc.y += c * bf2f(uv[idx].y);
        acc.z += c * bf2f(uv[idx].z); acc.w += c * bf2f(uv[idx].w);
    }
    // reduce across the 4 level-lanes (stride 8 within the unit)
    acc.x += __shfl_xor(acc.x, 8);  acc.y += __shfl_xor(acc.y, 8);
    acc.z += __shfl_xor(acc.z, 8);  acc.w += __shfl_xor(acc.w, 8);
    acc.x += __shfl_xor(acc.x, 16); acc.y += __shfl_xor(acc.y, 16);
    acc.z += __shfl_xor(acc.z, 16); acc.w += __shfl_xor(acc.w, 16);
    if (l == 0) {
        ushort4 o;
        o.x = f2bf(acc.x); o.y = f2bf(acc.y); o.z = f2bf(acc.z); o.w = f2bf(acc.w);
        *(ushort4*)(attn_bf + (size_t)r * 256 + h * 32 + d4 * 4) = o;
    }
}

// ---------------------------------------------------------------------------
// In-place LayerNorm over 256 cols; optional bf16 copy-out.
// ---------------------------------------------------------------------------
template<bool WRITE_BF>
__global__ __launch_bounds__(256) void layernorm_k(
    float* __restrict__ x, const float* __restrict__ g, const float* __restrict__ b,
    unsigned short* __restrict__ xbf)
{
    int lane = threadIdx.x & 63;
    int wv = threadIdx.x >> 6;
    int row = blockIdx.x * 4 + wv;
    int c = lane << 2;
    float4 v = *(const float4*)(x + (size_t)row * 256 + c);
    float s = v.x + v.y + v.z + v.w;
    #pragma unroll
    for (int o = 1; o < 64; o <<= 1) s += __shfl_xor(s, o);
    float mu = s * (1.f / 256.f);
    float d0 = v.x - mu, d1 = v.y - mu, d2 = v.z - mu, d3 = v.w - mu;
    float vs = d0 * d0 + d1 * d1 + d2 * d2 + d3 * d3;
    #pragma unroll
    for (int o = 1; o < 64; o <<= 1) vs += __shfl_xor(vs, o);
    float rstd = rsqrtf(vs * (1.f / 256.f) + 1e-5f);
    float4 gg = *(const float4*)(g + c);
    float4 bb = *(const float4*)(b + c);
    float4 o4;
    o4.x = d0 * rstd * gg.x + bb.x;
    o4.y = d1 * rstd * gg.y + bb.y;
    o4.z = d2 * rstd * gg.z + bb.z;
    o4.w = d3 * rstd * gg.w + bb.w;
    *(float4*)(x + (size_t)row * 256 + c) = o4;
    if (WRITE_BF) {
        ushort4 ob;
        ob.x = f2bf(o4.x); ob.y = f2bf(o4.y); ob.z = f2bf(o4.z); ob.w = f2bf(o4.w);
        *(ushort4*)(xbf + (size_t)row * 256 + c) = ob;
    }
}

// ---------------------------------------------------------------------------
extern "C" void kernel_launch(void* const* d_in, const int* in_sizes, int n_in,
                              void* d_out, int out_size, void* d_ws, size_t ws_size,
                              hipStream_t stream)
{
    const float* src   = (const float*)d_in[0];
    const float* refp  = (const float*)d_in[2];
    const float* vw    = (const float*)d_in[3];
    const float* vb    = (const float*)d_in[4];
    const float* ofw   = (const float*)d_in[5];
    const float* ofb   = (const float*)d_in[6];
    const float* aww   = (const float*)d_in[7];
    const float* awb   = (const float*)d_in[8];
    const float* pw    = (const float*)d_in[9];
    const float* pb    = (const float*)d_in[10];
    const float* g1    = (const float*)d_in[11];
    const float* b1    = (const float*)d_in[12];
    const float* w1    = (const float*)d_in[13];
    const float* bi1   = (const float*)d_in[14];
    const float* w2    = (const float*)d_in[15];
    const float* bi2   = (const float*)d_in[16];
    const float* g2    = (const float*)d_in[17];
    const float* b2    = (const float*)d_in[18];

    float* ws = (float*)d_ws;
    float*          po        = ws;                               // 3,145,728 f
    float*          x1        = ws + 3145728;                     // 2,097,152 f
    unsigned short* value_bf  = (unsigned short*)(ws + 5242880);  // 2,097,152 us
    unsigned short* src_bf    = (unsigned short*)(ws + 6291456);  // 2,097,152 us
    unsigned short* x1_bf     = (unsigned short*)(ws + 7340032);
    unsigned short* attn_bf   = (unsigned short*)(ws + 8388608);
    unsigned short* hidden_bf = (unsigned short*)(ws + 9437184);  // 8,388,608 us
    unsigned short* Btcat     = (unsigned short*)(ws + 13631488); // 163,840 us
    unsigned short* pwT       = (unsigned short*)(ws + 13713408);
    unsigned short* w1T       = (unsigned short*)(ws + 13746176);
    unsigned short* w2T       = (unsigned short*)(ws + 13877248);
    float*          biascat   = ws + 14008320;                    // 640 f

    float* out_x   = (float*)d_out;
    float* out_loc = out_x + 2097152;

    dim3 blk(256);

    // --- weight prep (bf16, transposed) + src conversion ---
    f2bf_k<<<2048, blk, 0, stream>>>(src, src_bf, 524288);
    transT_k<<<dim3(8, 8),  blk, 0, stream>>>(vw,  Btcat, 256, 256,  256, 0);
    transT_k<<<dim3(8, 8),  blk, 0, stream>>>(ofw, Btcat, 256, 256,  256, 256);
    transT_k<<<dim3(4, 8),  blk, 0, stream>>>(aww, Btcat, 256, 128,  256, 512);
    transT_k<<<dim3(8, 8),  blk, 0, stream>>>(pw,  pwT,   256, 256,  256, 0);
    transT_k<<<dim3(32, 8), blk, 0, stream>>>(w1,  w1T,   256, 1024, 256, 0);
    transT_k<<<dim3(8, 32), blk, 0, stream>>>(w2,  w2T,  1024, 256, 1024, 0);
    biascat_k<<<3, blk, 0, stream>>>(vb, ofb, awb, biascat);

    // --- fused projections -> value_bf (compact) + po[8192][384]
    mfma_gemm_k<true, false, false, false><<<dim3(10, 64), blk, 0, stream>>>(
        src_bf, Btcat, biascat, nullptr, po, value_bf, ROWS, 640, 256);

    // --- loc + softmax + deformable gather -> out_loc, attn_bf
    fused_gather_k<<<8192, blk, 0, stream>>>(po, value_bf, refp, out_loc, attn_bf);

    // --- output projection + residual(src) -> x1, LN1 (+bf16 copy)
    mfma_gemm_k<false, false, false, true><<<dim3(4, 64), blk, 0, stream>>>(
        attn_bf, pwT, pb, src, x1, nullptr, ROWS, 256, 256);
    layernorm_k<true><<<2048, blk, 0, stream>>>(x1, g1, b1, x1_bf);

    // --- FFN ---
    mfma_gemm_k<false, true, true, false><<<dim3(16, 64), blk, 0, stream>>>(
        x1_bf, w1T, bi1, nullptr, hidden_bf, nullptr, ROWS, 1024, 256);
    mfma_gemm_k<false, false, false, true><<<dim3(4, 64), blk, 0, stream>>>(
        hidden_bf, w2T, bi2, x1, out_x, nullptr, ROWS, 256, 1024);
    layernorm_k<false><<<2048, blk, 0, stream>>>(out_x, g2, b2, nullptr);
}

// Round 7
// 191.112 us; speedup vs baseline: 1.5160x; 1.0847x over previous
//
#include <hip/hip_runtime.h>
#include <math.h>

#define ROWS   8192
#define LQ     4096
#define NHEAD  8
#define NLVL   4
#define NPTS   4
#define HDIM   32

typedef __attribute__((ext_vector_type(8))) short v8s;
typedef __attribute__((ext_vector_type(4))) float v4f;

__device__ __forceinline__ unsigned short f2bf(float x) {
    unsigned int u = __float_as_uint(x);
    u += 0x7fffu + ((u >> 16) & 1u);
    return (unsigned short)(u >> 16);
}
__device__ __forceinline__ float bf2f(unsigned short x) {
    return __uint_as_float(((unsigned int)x) << 16);
}

// async global -> LDS, 16B per lane; LDS dest = wave-uniform base + lane*16
__device__ __forceinline__ void glds16(const void* g, void* l) {
    __builtin_amdgcn_global_load_lds(
        (const __attribute__((address_space(1))) unsigned int*)g,
        (__attribute__((address_space(3))) unsigned int*)l, 16, 0, 0);
}

// ---------------------------------------------------------------------------
// Fused prep: [0,2048) f2bf(src); then 6 transposes; last block biascat.
// ---------------------------------------------------------------------------
__device__ __forceinline__ void trans_tile(const float* __restrict__ in,
                                           unsigned short* __restrict__ out,
                                           int K, int N, int ldout, int n_off,
                                           int bx, int by, int tid)
{
    __shared__ float t[32][33];
    int tx = tid & 31, ty = tid >> 5;           // 32 x 8
    int k0 = by << 5, n0 = bx << 5;
    #pragma unroll
    for (int i = 0; i < 4; i++)
        t[ty + i * 8][tx] = in[(size_t)(k0 + ty + i * 8) * N + n0 + tx];
    __syncthreads();
    #pragma unroll
    for (int i = 0; i < 4; i++)
        out[(size_t)(n_off + n0 + ty + i * 8) * ldout + k0 + tx] = f2bf(t[tx][ty + i * 8]);
}

__global__ __launch_bounds__(256) void prep_k(
    const float* __restrict__ src, unsigned short* __restrict__ src_bf,
    const float* __restrict__ vw, const float* __restrict__ ofw,
    const float* __restrict__ aww, const float* __restrict__ pw,
    const float* __restrict__ w1, const float* __restrict__ w2,
    unsigned short* __restrict__ Btcat, unsigned short* __restrict__ pwT,
    unsigned short* __restrict__ w1T, unsigned short* __restrict__ w2T,
    const float* __restrict__ vb, const float* __restrict__ ofb,
    const float* __restrict__ awb, float* __restrict__ biascat)
{
    int bid = blockIdx.x, tid = threadIdx.x;
    if (bid < 2048) {
        int i = bid * 256 + tid;                 // 524288 float4s
        float4 v = ((const float4*)src)[i];
        ushort4 o;
        o.x = f2bf(v.x); o.y = f2bf(v.y); o.z = f2bf(v.z); o.w = f2bf(v.w);
        ((ushort4*)src_bf)[i] = o;
    } else if (bid < 2112) {                     // vw: 8x8
        int t = bid - 2048; trans_tile(vw, Btcat, 256, 256, 256, 0, t & 7, t >> 3, tid);
    } else if (bid < 2176) {                     // ofw: 8x8
        int t = bid - 2112; trans_tile(ofw, Btcat, 256, 256, 256, 256, t & 7, t >> 3, tid);
    } else if (bid < 2208) {                     // aww: 4x8
        int t = bid - 2176; trans_tile(aww, Btcat, 256, 128, 256, 512, t & 3, t >> 2, tid);
    } else if (bid < 2272) {                     // pw: 8x8
        int t = bid - 2208; trans_tile(pw, pwT, 256, 256, 256, 0, t & 7, t >> 3, tid);
    } else if (bid < 2528) {                     // w1: 32x8
        int t = bid - 2272; trans_tile(w1, w1T, 256, 1024, 256, 0, t & 31, t >> 5, tid);
    } else if (bid < 2784) {                     // w2: 8x32
        int t = bid - 2528; trans_tile(w2, w2T, 1024, 256, 1024, 0, t & 7, t >> 3, tid);
    } else {                                     // biascat
        biascat[tid] = vb[tid];
        biascat[tid + 256] = ofb[tid];
        if (tid < 128) biascat[tid + 512] = awb[tid];
    }
}

// ---------------------------------------------------------------------------
// bf16 MFMA GEMM with global_load_lds staging.
// BM=128, BN=64, BK=32; 256 threads = 4 waves (2x2), wave = 64x32 (4x2 MFMA).
// XOR-swizzled LDS chunk layout: physical chunk c=row*4+s holds K-slot
// kq=(s+(row>>2))&3 -> staging is lane-contiguous (HW requirement) and
// fragment b128 reads hit each bank exactly 2x (free).
// PROJ mode (N=640): cols [0,256) scatter bf16 into compact value layout
// [ (b*4+l)*8+h ][pix][d] ; cols [256,640) -> po[row][col-256] fp32.
// ---------------------------------------------------------------------------
template<bool PROJ, bool OUTBF, bool RELU, bool RES>
__global__ __launch_bounds__(256) void mfma_gemm_k(
    const unsigned short* __restrict__ A,   // bf16 [M][K]
    const unsigned short* __restrict__ Bt,  // bf16 [N][K]
    const float* __restrict__ bias,
    const float* __restrict__ res,
    void* __restrict__ Cout,
    unsigned short* __restrict__ vbf,       // PROJ only
    int M, int N, int K)
{
    __shared__ __align__(16) unsigned short As[4096];   // 512 chunks x 16B
    __shared__ __align__(16) unsigned short Bs[2048];   // 256 chunks x 16B
    const int tid = threadIdx.x;
    const int row0 = blockIdx.y << 7, col0 = blockIdx.x << 6;
    const int wid = tid >> 6, lane = tid & 63;
    const int wm = wid & 1, wn = wid >> 1;
    const int lr = lane & 15, kq = lane >> 4;

    v4f acc[4][2];
    #pragma unroll
    for (int i = 0; i < 4; i++)
        #pragma unroll
        for (int j = 0; j < 2; j++) acc[i][j] = (v4f){0.f, 0.f, 0.f, 0.f};

    for (int k0 = 0; k0 < K; k0 += 32) {
        __syncthreads();                      // previous compute done
        // A: 512 chunks, 2 issues/wave; B: 256 chunks, 1 issue/wave
        #pragma unroll
        for (int i = 0; i < 2; i++) {
            int c = wid * 128 + i * 64 + lane;
            int row = c >> 2;
            int kk = ((c & 3) + (row >> 2)) & 3;
            glds16(A + (size_t)(row0 + row) * K + k0 + kk * 8,
                   &As[(wid * 128 + i * 64) * 8]);
        }
        {
            int c = wid * 64 + lane;
            int row = c >> 2;
            int kk = ((c & 3) + (row >> 2)) & 3;
            glds16(Bt + (size_t)(col0 + row) * K + k0 + kk * 8,
                   &Bs[wid * 512]);
        }
        __syncthreads();                      // vmcnt(0) drain + barrier
        v8s bf[2];
        #pragma unroll
        for (int nt = 0; nt < 2; nt++) {
            int row = wn * 32 + nt * 16 + lr;
            int s = (kq - (row >> 2)) & 3;
            bf[nt] = *(const v8s*)(&Bs[(row * 4 + s) * 8]);
        }
        #pragma unroll
        for (int mt = 0; mt < 4; mt++) {
            int row = wm * 64 + mt * 16 + lr;
            int s = (kq - (row >> 2)) & 3;
            v8s af = *(const v8s*)(&As[(row * 4 + s) * 8]);
            #pragma unroll
            for (int nt = 0; nt < 2; nt++)
                acc[mt][nt] = __builtin_amdgcn_mfma_f32_16x16x32_bf16(af, bf[nt], acc[mt][nt], 0, 0, 0);
        }
    }

    const int rq = lane >> 4;
    #pragma unroll
    for (int mt = 0; mt < 4; mt++) {
        #pragma unroll
        for (int nt = 0; nt < 2; nt++) {
            int col = col0 + wn * 32 + nt * 16 + lr;
            float bv = bias[col];
            #pragma unroll
            for (int i = 0; i < 4; i++) {
                int row = row0 + wm * 64 + mt * 16 + rq * 4 + i;
                float v = acc[mt][nt][i] + bv;
                if (RELU) v = fmaxf(v, 0.f);
                if (RES)  v += res[(size_t)row * N + col];
                if (PROJ) {
                    if (col0 < 256) {
                        int b = row >> 12, rb = row & 4095;
                        int l = rb >> 10, pix = rb & 1023;
                        int h = col >> 5, d = col & 31;
                        size_t idx = ((size_t)(((b << 2) + l) * 8 + h) << 15) + (pix << 5) + d;
                        vbf[idx] = f2bf(v);
                    } else {
                        ((float*)Cout)[(size_t)row * 384 + col - 256] = v;
                    }
                } else if (OUTBF) {
                    ((unsigned short*)Cout)[(size_t)row * N + col] = f2bf(v);
                } else {
                    ((float*)Cout)[(size_t)row * N + col] = v;
                }
            }
        }
    }
}

// ---------------------------------------------------------------------------
// Fused gather, level-split (R5-proven): thread (u,l,d4) owns one level of
// one (r,h); softmax-16 and level reduction via __shfl_xor(8/16).
// ---------------------------------------------------------------------------
__global__ __launch_bounds__(256) void fused_gather_k(
    const float* __restrict__ po,              // [ROWS][384] offsets|logits
    const unsigned short* __restrict__ vbf,    // [64][1024][32] bf16
    const float* __restrict__ refp,            // [ROWS][8]
    float* __restrict__ out_loc,               // [ROWS][256]
    unsigned short* __restrict__ attn_bf)      // [ROWS][256] bf16
{
    int tid = threadIdx.x;
    int u = tid >> 5, l = (tid >> 3) & 3, d4 = tid & 7;
    int gid = blockIdx.x * 8 + u;              // r*8 + h
    int h = gid & 7, r = gid >> 3;
    int b = r >> 12;
    const float* prow = po + (size_t)r * 384;

    float2 rp = *(const float2*)(refp + (size_t)r * 8 + l * 2);

    float off[8];
    *(float4*)(off)     = *(const float4*)(prow + h * 32 + l * 8);
    *(float4*)(off + 4) = *(const float4*)(prow + h * 32 + l * 8 + 4);
    float locv[8];
    #pragma unroll
    for (int k = 0; k < 8; k++)
        locv[k] = ((k & 1) ? rp.y : rp.x) + off[k] * (1.f / 32.f);
    out_loc[(size_t)r * 256 + h * 32 + l * 8 + d4] = locv[d4];

    float w4[4];
    *(float4*)(w4) = *(const float4*)(prow + 256 + h * 16 + l * 4);
    float m = fmaxf(fmaxf(w4[0], w4[1]), fmaxf(w4[2], w4[3]));
    m = fmaxf(m, __shfl_xor(m, 8));
    m = fmaxf(m, __shfl_xor(m, 16));
    float s = 0.f;
    #pragma unroll
    for (int p = 0; p < 4; p++) { w4[p] = __expf(w4[p] - m); s += w4[p]; }
    s += __shfl_xor(s, 8);
    s += __shfl_xor(s, 16);
    float inv = 1.f / s;

    const unsigned short* vbase =
        vbf + (((size_t)(((b << 2) + l) * 8 + h)) << 15) + d4 * 4;
    ushort4 uv[16];
    float cw[16];
    #pragma unroll
    for (int p = 0; p < 4; p++) {
        float xf = locv[p * 2] * 32.f - 0.5f, yf = locv[p * 2 + 1] * 32.f - 0.5f;
        float x0f = floorf(xf), y0f = floorf(yf);
        float fx = xf - x0f, fy = yf - y0f;
        int x0 = (int)x0f, y0 = (int)y0f;
        float wgt = w4[p] * inv;
        #pragma unroll
        for (int dy = 0; dy < 2; dy++) {
            #pragma unroll
            for (int dx = 0; dx < 2; dx++) {
                int idx = p * 4 + dy * 2 + dx;
                int xi = x0 + dx, yi = y0 + dy;
                float wt = (dx ? fx : 1.f - fx) * (dy ? fy : 1.f - fy);
                bool valid = (xi >= 0) & (xi < 32) & (yi >= 0) & (yi < 32);
                int xc = min(max(xi, 0), 31), yc = min(max(yi, 0), 31);
                cw[idx] = valid ? (wgt * wt) : 0.f;
                uv[idx] = *(const ushort4*)(vbase + (size_t)((yc << 5) + xc) * 32);
            }
        }
    }
    float4 acc = {0.f, 0.f, 0.f, 0.f};
    #pragma unroll
    for (int idx = 0; idx < 16; idx++) {
        float c = cw[idx];
        acc.x += c * bf2f(uv[idx].x); acc.y += c * bf2f(uv[idx].y);
        acc.z += c * bf2f(uv[idx].z); acc.w += c * bf2f(uv[idx].w);
    }
    acc.x += __shfl_xor(acc.x, 8);  acc.y += __shfl_xor(acc.y, 8);
    acc.z += __shfl_xor(acc.z, 8);  acc.w += __shfl_xor(acc.w, 8);
    acc.x += __shfl_xor(acc.x, 16); acc.y += __shfl_xor(acc.y, 16);
    acc.z += __shfl_xor(acc.z, 16); acc.w += __shfl_xor(acc.w, 16);
    if (l == 0) {
        ushort4 o;
        o.x = f2bf(acc.x); o.y = f2bf(acc.y); o.z = f2bf(acc.z); o.w = f2bf(acc.w);
        *(ushort4*)(attn_bf + (size_t)r * 256 + h * 32 + d4 * 4) = o;
    }
}

// ---------------------------------------------------------------------------
// In-place LayerNorm over 256 cols; optional bf16 copy-out.
// ---------------------------------------------------------------------------
template<bool WRITE_BF>
__global__ __launch_bounds__(256) void layernorm_k(
    float* __restrict__ x, const float* __restrict__ g, const float* __restrict__ b,
    unsigned short* __restrict__ xbf)
{
    int lane = threadIdx.x & 63;
    int wv = threadIdx.x >> 6;
    int row = blockIdx.x * 4 + wv;
    int c = lane << 2;
    float4 v = *(const float4*)(x + (size_t)row * 256 + c);
    float s = v.x + v.y + v.z + v.w;
    #pragma unroll
    for (int o = 1; o < 64; o <<= 1) s += __shfl_xor(s, o);
    float mu = s * (1.f / 256.f);
    float d0 = v.x - mu, d1 = v.y - mu, d2 = v.z - mu, d3 = v.w - mu;
    float vs = d0 * d0 + d1 * d1 + d2 * d2 + d3 * d3;
    #pragma unroll
    for (int o = 1; o < 64; o <<= 1) vs += __shfl_xor(vs, o);
    float rstd = rsqrtf(vs * (1.f / 256.f) + 1e-5f);
    float4 gg = *(const float4*)(g + c);
    float4 bb = *(const float4*)(b + c);
    float4 o4;
    o4.x = d0 * rstd * gg.x + bb.x;
    o4.y = d1 * rstd * gg.y + bb.y;
    o4.z = d2 * rstd * gg.z + bb.z;
    o4.w = d3 * rstd * gg.w + bb.w;
    *(float4*)(x + (size_t)row * 256 + c) = o4;
    if (WRITE_BF) {
        ushort4 ob;
        ob.x = f2bf(o4.x); ob.y = f2bf(o4.y); ob.z = f2bf(o4.z); ob.w = f2bf(o4.w);
        *(ushort4*)(xbf + (size_t)row * 256 + c) = ob;
    }
}

// ---------------------------------------------------------------------------
extern "C" void kernel_launch(void* const* d_in, const int* in_sizes, int n_in,
                              void* d_out, int out_size, void* d_ws, size_t ws_size,
                              hipStream_t stream)
{
    const float* src   = (const float*)d_in[0];
    const float* refp  = (const float*)d_in[2];
    const float* vw    = (const float*)d_in[3];
    const float* vb    = (const float*)d_in[4];
    const float* ofw   = (const float*)d_in[5];
    const float* ofb   = (const float*)d_in[6];
    const float* aww   = (const float*)d_in[7];
    const float* awb   = (const float*)d_in[8];
    const float* pw    = (const float*)d_in[9];
    const float* pb    = (const float*)d_in[10];
    const float* g1    = (const float*)d_in[11];
    const float* b1    = (const float*)d_in[12];
    const float* w1    = (const float*)d_in[13];
    const float* bi1   = (const float*)d_in[14];
    const float* w2    = (const float*)d_in[15];
    const float* bi2   = (const float*)d_in[16];
    const float* g2    = (const float*)d_in[17];
    const float* b2    = (const float*)d_in[18];

    float* ws = (float*)d_ws;
    float*          po        = ws;                               // 3,145,728 f
    float*          x1        = ws + 3145728;                     // 2,097,152 f
    unsigned short* value_bf  = (unsigned short*)(ws + 5242880);  // 2,097,152 us
    unsigned short* src_bf    = (unsigned short*)(ws + 6291456);  // 2,097,152 us
    unsigned short* x1_bf     = (unsigned short*)(ws + 7340032);
    unsigned short* attn_bf   = (unsigned short*)(ws + 8388608);
    unsigned short* hidden_bf = (unsigned short*)(ws + 9437184);  // 8,388,608 us
    unsigned short* Btcat     = (unsigned short*)(ws + 13631488); // 163,840 us
    unsigned short* pwT       = (unsigned short*)(ws + 13713408);
    unsigned short* w1T       = (unsigned short*)(ws + 13746176);
    unsigned short* w2T       = (unsigned short*)(ws + 13877248);
    float*          biascat   = ws + 14008320;                    // 640 f

    float* out_x   = (float*)d_out;
    float* out_loc = out_x + 2097152;

    dim3 blk(256);

    // --- all prep in one launch ---
    prep_k<<<2785, blk, 0, stream>>>(src, src_bf, vw, ofw, aww, pw, w1, w2,
                                     Btcat, pwT, w1T, w2T, vb, ofb, awb, biascat);

    // --- fused projections -> value_bf (compact) + po[8192][384]
    mfma_gemm_k<true, false, false, false><<<dim3(10, 64), blk, 0, stream>>>(
        src_bf, Btcat, biascat, nullptr, po, value_bf, ROWS, 640, 256);

    // --- loc + softmax + deformable gather -> out_loc, attn_bf
    fused_gather_k<<<8192, blk, 0, stream>>>(po, value_bf, refp, out_loc, attn_bf);

    // --- output projection + residual(src) -> x1, LN1 (+bf16 copy)
    mfma_gemm_k<false, false, false, true><<<dim3(4, 64), blk, 0, stream>>>(
        attn_bf, pwT, pb, src, x1, nullptr, ROWS, 256, 256);
    layernorm_k<true><<<2048, blk, 0, stream>>>(x1, g1, b1, x1_bf);

    // --- FFN ---
    mfma_gemm_k<false, true, true, false><<<dim3(16, 64), blk, 0, stream>>>(
        x1_bf, w1T, bi1, nullptr, hidden_bf, nullptr, ROWS, 1024, 256);
    mfma_gemm_k<false, false, false, true><<<dim3(4, 64), blk, 0, stream>>>(
        hidden_bf, w2T, bi2, x1, out_x, nullptr, ROWS, 256, 1024);
    layernorm_k<false><<<2048, blk, 0, stream>>>(out_x, g2, b2, nullptr);
}